// Round 1
// baseline (1142.009 us; speedup 1.0000x reference)
//
#include <hip/hip_runtime.h>
#include <math.h>

#ifndef M_PI
#define M_PI 3.14159265358979323846
#endif

#define ROWS 128
#define NN   4096
#define M2   8192

// ws byte offsets
#define CA_OFF 0          // float2[8192]   chirp cA[m] = chirp[4096+m]
#define EF_OFF 65536      // float2[16384]  Ef[d+8192] = E[d]
#define WT_OFF 196608     // float[8192]    Wt[delta+4095], delta in [-4095,4095]
#define SC_OFF 229376     // float2         Aphi/128
#define BO_OFF 229440     // float[128*4096] odd-sample interpolation

__global__ __launch_bounds__(256) void build_tables_k(const float* __restrict__ order,
                                                      char* __restrict__ ws) {
    const int t = threadIdx.x;
    const double a   = (double)order[0];
    const double phi = a * (M_PI * 0.5);
    const double sp  = sin(phi);
    const double alpha = -M_PI * tan(phi * 0.5);   // phase coeff of chirp
    const double betac =  M_PI / sp;               // phase coeff of E
    float2* cA = (float2*)(ws + CA_OFF);
    float2* Ef = (float2*)(ws + EF_OFF);
    float*  Wt = (float*) (ws + WT_OFF);
    float2* sc = (float2*)(ws + SC_OFF);
    for (int m = t; m < M2; m += 256) {
        double xg = (double)(m - 4096) * (1.0 / 128.0);
        double th = alpha * (xg * xg);
        cA[m] = make_float2((float)cos(th), (float)sin(th));
    }
    for (int k = t; k < 16384; k += 256) {
        double d  = (double)(k - 8192) * (1.0 / 128.0);
        double th = betac * (d * d);
        Ef[k] = make_float2((float)cos(th), (float)sin(th));
    }
    for (int k = t; k < 8191; k += 256) {
        int    delta = k - 4095;
        double th = M_PI * (double)(2 * delta + 1) / 8192.0;
        double v  = (cos(th) / sin(th)) * (1.0 / 4096.0);
        if (delta & 1) v = -v;                      // (-1)^delta, works for negatives
        Wt[k] = (float)v;
    }
    if (t == 0) {
        double sgn = (sp >= 0.0) ? 1.0 : -1.0;
        double ang = -(M_PI * sgn * 0.25 - phi * 0.5);
        double amp = 1.0 / sqrt(fabs(sp));
        sc[0] = make_float2((float)(cos(ang) * amp / 128.0),
                            (float)(sin(ang) * amp / 128.0));
    }
}

// odd samples of the 2x sinc interpolation: bodd[row][i] = biz[row][2i+1]
__global__ __launch_bounds__(256) void bizodd_k(const float* __restrict__ x,
                                                const char* __restrict__ ws,
                                                float* __restrict__ bodd) {
    __shared__ float xs[NN];
    __shared__ float Ws[5120];
    const float* Wt = (const float*)(ws + WT_OFF);
    const int bid = blockIdx.x;
    const int row = bid >> 2;
    const int i0  = (bid & 3) * 1024;
    const int t   = threadIdx.x;
    for (int j = t; j < NN; j += 256) xs[j] = x[row * NN + j];
    for (int k = t; k < 5119; k += 256) Ws[k] = Wt[i0 + k];  // global idx i0+k <= 8190
    __syncthreads();
    float acc0 = 0.f, acc1 = 0.f, acc2 = 0.f, acc3 = 0.f;
    const int b = t + 4095;
#pragma unroll 4
    for (int j = 0; j < NN; ++j) {
        const float xv = xs[j];
        const int idx = b - j;            // local = (i - j + 4095) - i0
        acc0 = fmaf(xv, Ws[idx      ], acc0);
        acc1 = fmaf(xv, Ws[idx + 256], acc1);
        acc2 = fmaf(xv, Ws[idx + 512], acc2);
        acc3 = fmaf(xv, Ws[idx + 768], acc3);
    }
    float* dst = bodd + row * NN + i0 + t;
    dst[0]   = acc0;
    dst[256] = acc1;
    dst[512] = acc2;
    dst[768] = acc3;
}

// out[row][o] = scale * cA[2o] * sum_m (biz[m]*cA[m]) * E[2o-m], o in [0,4096)
__global__ __launch_bounds__(256) void frft_conv_k(const float* __restrict__ x,
                                                   const char* __restrict__ ws,
                                                   const float* __restrict__ bodd,
                                                   float* __restrict__ out,
                                                   int write_complex) {
    __shared__ float2 wsd[M2];   // 64 KB: w[m] = biz[m] * cA[m]
    const float2* cA = (const float2*)(ws + CA_OFF);
    const float2* Ef = (const float2*)(ws + EF_OFF);
    const float2* sc = (const float2*)(ws + SC_OFF);
    const int bid = blockIdx.x;
    const int row = bid >> 2;
    const int o0  = (bid & 3) * 1024;
    const int t   = threadIdx.x;

    for (int m = t; m < M2; m += 256) {
        const int   h = m >> 1;
        const float b = (m & 1) ? bodd[row * NN + h] : x[row * NN + h];
        const float2 c = cA[m];
        wsd[m] = make_float2(b * c.x, b * c.y);
    }
    __syncthreads();

    float ar0 = 0.f, ai0 = 0.f, ar1 = 0.f, ai1 = 0.f;
    float ar2 = 0.f, ai2 = 0.f, ar3 = 0.f, ai3 = 0.f;
    const float2* E0 = Ef + (2 * (o0 + t) + 8192);
#pragma unroll 4
    for (int m = 0; m < M2; ++m) {
        const float2 w  = wsd[m];
        const float2 e0 = E0[       -m];
        const float2 e1 = E0[ 512 - m];
        const float2 e2 = E0[1024 - m];
        const float2 e3 = E0[1536 - m];
        ar0 = fmaf(w.x, e0.x, ar0); ar0 = fmaf(-w.y, e0.y, ar0);
        ai0 = fmaf(w.x, e0.y, ai0); ai0 = fmaf( w.y, e0.x, ai0);
        ar1 = fmaf(w.x, e1.x, ar1); ar1 = fmaf(-w.y, e1.y, ar1);
        ai1 = fmaf(w.x, e1.y, ai1); ai1 = fmaf( w.y, e1.x, ai1);
        ar2 = fmaf(w.x, e2.x, ar2); ar2 = fmaf(-w.y, e2.y, ar2);
        ai2 = fmaf(w.x, e2.y, ai2); ai2 = fmaf( w.y, e2.x, ai2);
        ar3 = fmaf(w.x, e3.x, ar3); ar3 = fmaf(-w.y, e3.y, ar3);
        ai3 = fmaf(w.x, e3.y, ai3); ai3 = fmaf( w.y, e3.x, ai3);
    }

    const float2 s = *sc;
#define EMIT(K, AR, AI)                                                        \
    {                                                                          \
        const int o = o0 + t + 256 * (K);                                      \
        const float2 c = cA[2 * o];                                            \
        const float tr = (AR) * c.x - (AI) * c.y;                              \
        const float ti = (AR) * c.y + (AI) * c.x;                              \
        float rr = tr * s.x - ti * s.y;                                        \
        float ri = tr * s.y + ti * s.x;                                        \
        if (o == 0) { rr *= 2.f; ri *= 2.f; }                                  \
        const int gi = row * NN + o;                                           \
        if (write_complex) { out[2 * gi] = rr; out[2 * gi + 1] = ri; }         \
        else               { out[gi] = rr; }                                   \
    }
    EMIT(0, ar0, ai0)
    EMIT(1, ar1, ai1)
    EMIT(2, ar2, ai2)
    EMIT(3, ar3, ai3)
#undef EMIT
}

extern "C" void kernel_launch(void* const* d_in, const int* in_sizes, int n_in,
                              void* d_out, int out_size, void* d_ws, size_t ws_size,
                              hipStream_t stream) {
    const float* x     = (const float*)d_in[0];
    const float* order = (const float*)d_in[1];
    float* out = (float*)d_out;
    char*  ws  = (char*)d_ws;
    float* bodd = (float*)(ws + BO_OFF);
    const int write_complex = (out_size >= 2 * ROWS * NN) ? 1 : 0;

    hipLaunchKernelGGL(build_tables_k, dim3(1), dim3(256), 0, stream, order, ws);
    hipLaunchKernelGGL(bizodd_k, dim3(ROWS * 4), dim3(256), 0, stream, x, ws, bodd);
    hipLaunchKernelGGL(frft_conv_k, dim3(ROWS * 4), dim3(256), 0, stream,
                       x, ws, bodd, out, write_complex);
}

// Round 3
// 171.805 us; speedup vs baseline: 6.6471x; 6.6471x over previous
//
#include <hip/hip_runtime.h>
#include <math.h>

#ifndef M_PI
#define M_PI 3.14159265358979323846
#endif

#define ROWS 128
#define NN   4096

// ws byte offsets
#define TW_OFF   0        // float2[4096]  twid[k] = exp(-2*pi*i*k/8192)
#define CA_OFF   32768    // float2[8192]  cA[m] = chirp[4096+m]
#define GEIN_OFF 98304    // float2[8192]  Ec_even (time domain)
#define GOIN_OFF 163840   // float2[8192]  Ec_odd  (time domain)
#define GE_OFF   229376   // float2[8192]  FFT(Ec_even)
#define GO_OFF   294912   // float2[8192]  FFT(Ec_odd)
#define SC_OFF   360448   // float2        Aphi/128

__device__ __forceinline__ float2 cmul(float2 a, float2 b) {
    return make_float2(a.x * b.x - a.y * b.y, a.x * b.y + a.y * b.x);
}

// In-place radix-2 DIT FFT on LDS. Twiddle table is exp(-2*pi*i*k/8192),
// k in [0,4096); for stage group size m=2^s the needed angle -2*pi*pos/m
// equals table index pos << (13 - s). Valid for n = 4096 or 8192.
// INV=1: conjugate twiddles (no 1/n scaling — caller folds it).
template<int INV>
__device__ void fft_lds(float2* buf, const float2* __restrict__ twid,
                        int n, int logn, int tid, int nthr) {
    __syncthreads();
    // bit-reversal permutation (each unordered pair swapped exactly once)
    for (int i = tid; i < n; i += nthr) {
        int j = (int)(__brev((unsigned)i) >> (32 - logn));
        if (j > i) { float2 t = buf[i]; buf[i] = buf[j]; buf[j] = t; }
    }
    __syncthreads();
    for (int s = 1; s <= logn; ++s) {
        const int half = 1 << (s - 1);
        const int shift = 13 - s;
        for (int k = tid; k < (n >> 1); k += nthr) {
            const int pos = k & (half - 1);
            const int i0 = ((k >> (s - 1)) << s) + pos;
            const int i1 = i0 + half;
            float2 tw = twid[pos << shift];
            if (INV) tw.y = -tw.y;
            const float2 u = buf[i0];
            const float2 v = cmul(buf[i1], tw);
            buf[i0] = make_float2(u.x + v.x, u.y + v.y);
            buf[i1] = make_float2(u.x - v.x, u.y - v.y);
        }
        __syncthreads();
    }
}

__global__ __launch_bounds__(256) void build_tables_k(const float* __restrict__ order,
                                                      char* __restrict__ ws) {
    const int gid  = blockIdx.x * 256 + threadIdx.x;
    const int nthr = gridDim.x * 256;
    const double a    = (double)order[0];
    const double phi  = a * (M_PI * 0.5);
    const double sp   = sin(phi);
    const double alph = -M_PI * tan(phi * 0.5);
    const double beta = M_PI / sp;
    float2* twid = (float2*)(ws + TW_OFF);
    float2* cA   = (float2*)(ws + CA_OFF);
    float2* gein = (float2*)(ws + GEIN_OFF);
    float2* goin = (float2*)(ws + GOIN_OFF);
    float2* sc   = (float2*)(ws + SC_OFF);
    for (int k = gid; k < 4096; k += nthr) {
        double th = -2.0 * M_PI * (double)k / 8192.0;
        twid[k] = make_float2((float)cos(th), (float)sin(th));
    }
    for (int m = gid; m < 8192; m += nthr) {
        double xg = (double)(m - 4096) * (1.0 / 128.0);
        double th = alph * xg * xg;
        cA[m] = make_float2((float)cos(th), (float)sin(th));
    }
    for (int q = gid; q < 8192; q += nthr) {
        // even-parity kernel: E[2q] with circular wrap (slot 4096 unused)
        double de = (q < 4096) ? (double)(2 * q) : (double)(2 * q - 16384);
        double u  = de * (1.0 / 128.0);
        double te = beta * u * u;
        gein[q] = make_float2((float)cos(te), (float)sin(te));
        // odd-parity kernel: E[2q-1] with circular wrap
        double dl = (q < 4096) ? (double)(2 * q - 1) : (double)(2 * q - 16385);
        double v  = dl * (1.0 / 128.0);
        double to = beta * v * v;
        goin[q] = make_float2((float)cos(to), (float)sin(to));
    }
    if (gid == 0) {
        double sgn = (sp >= 0.0) ? 1.0 : -1.0;
        double ang = -(M_PI * sgn * 0.25 - phi * 0.5);
        double amp = 1.0 / sqrt(fabs(sp));
        sc[0] = make_float2((float)(cos(ang) * amp / 128.0),
                            (float)(sin(ang) * amp / 128.0));
    }
}

// FFT the two conv kernels once: block 0 -> GE, block 1 -> GO
__global__ __launch_bounds__(512) void g_fft_k(char* __restrict__ ws) {
    __shared__ float2 buf[8192];
    const float2* twid = (const float2*)(ws + TW_OFF);
    const float2* src  = (const float2*)(ws + (blockIdx.x == 0 ? GEIN_OFF : GOIN_OFF));
    float2*       dst  = (float2*)      (ws + (blockIdx.x == 0 ? GE_OFF   : GO_OFF));
    for (int i = threadIdx.x; i < 8192; i += 512) buf[i] = src[i];
    fft_lds<0>(buf, twid, 8192, 13, threadIdx.x, 512);
    for (int i = threadIdx.x; i < 8192; i += 512) dst[i] = buf[i];
}

__global__ __launch_bounds__(512) void row_k(const float* __restrict__ x,
                                             const char* __restrict__ ws,
                                             float* __restrict__ out,
                                             int write_complex) {
    __shared__ float2 buf[8192];   // 64 KB
    const float2* twid = (const float2*)(ws + TW_OFF);
    const float2* cA   = (const float2*)(ws + CA_OFF);
    const float2* GE   = (const float2*)(ws + GE_OFF);
    const float2* GO   = (const float2*)(ws + GO_OFF);
    const float2  sc   = *(const float2*)(ws + SC_OFF);
    const int row = blockIdx.x;
    const int tid = threadIdx.x;

    // (a) load row, FFT_4096
    for (int i = tid; i < NN; i += 512) buf[i] = make_float2(x[row * NN + i], 0.f);
    fft_lds<0>(buf, twid, 4096, 12, tid, 512);

    // (b) zero-stuffed-interpolation spectrum: keep k<2048 (in place),
    //     copy X[2048..4095] -> [6144..8191], zero [2048..6143]
    for (int i = tid; i < 2048; i += 512) buf[6144 + i] = buf[2048 + i];
    __syncthreads();
    for (int i = tid; i < 4096; i += 512) buf[2048 + i] = make_float2(0.f, 0.f);
    fft_lds<1>(buf, twid, 8192, 13, tid, 512);   // -> biz*8192 in Re

    // (c) w[m] = (2/8192)*Re * cA[m]
    const float s2 = 2.0f / 8192.0f;
    for (int m = tid; m < 8192; m += 512) {
        const float b  = buf[m].x * s2;
        const float2 c = cA[m];
        buf[m] = make_float2(b * c.x, b * c.y);
    }
    __syncthreads();

    // (d) parity split: stash w_odd in regs, compact w_even zero-padded
    float2 wo[8], wet[8];
#pragma unroll
    for (int j = 0; j < 8; ++j) {
        const int p = tid + 512 * j;
        wo[j]  = buf[2 * p + 1];
        wet[j] = buf[2 * p];
    }
    __syncthreads();
#pragma unroll
    for (int j = 0; j < 8; ++j) {
        const int p = tid + 512 * j;
        buf[p]        = wet[j];
        buf[4096 + p] = make_float2(0.f, 0.f);
    }
    fft_lds<0>(buf, twid, 8192, 13, tid, 512);   // -> What_even

    // (e) stash What_even in regs, FFT w_odd
    float2 weh[16];
#pragma unroll
    for (int j = 0; j < 16; ++j) weh[j] = buf[tid + 512 * j];
    __syncthreads();
#pragma unroll
    for (int j = 0; j < 8; ++j) {
        const int p = tid + 512 * j;
        buf[p]        = wo[j];
        buf[4096 + p] = make_float2(0.f, 0.f);
    }
    fft_lds<0>(buf, twid, 8192, 13, tid, 512);   // -> What_odd

    // (f) Yhat = What_e*GE + What_o*GO, then inverse FFT
#pragma unroll
    for (int j = 0; j < 16; ++j) {
        const int k = tid + 512 * j;
        const float2 ye = cmul(weh[j], GE[k]);
        const float2 yo = cmul(buf[k], GO[k]);
        buf[k] = make_float2(ye.x + yo.x, ye.y + yo.y);
    }
    fft_lds<1>(buf, twid, 8192, 13, tid, 512);   // -> y*8192

    // (g) out[o] = y[o]/8192 * cA[2o] * sc, o==0 doubled
    const float is = 1.0f / 8192.0f;
    for (int o = tid; o < NN; o += 512) {
        const float2 v = make_float2(buf[o].x * is, buf[o].y * is);
        const float2 t = cmul(v, cA[2 * o]);
        float2 r = cmul(t, sc);
        if (o == 0) { r.x *= 2.f; r.y *= 2.f; }
        const int gi = row * NN + o;
        if (write_complex) { out[2 * gi] = r.x; out[2 * gi + 1] = r.y; }
        else               { out[gi] = r.x; }
    }
}

extern "C" void kernel_launch(void* const* d_in, const int* in_sizes, int n_in,
                              void* d_out, int out_size, void* d_ws, size_t ws_size,
                              hipStream_t stream) {
    const float* x     = (const float*)d_in[0];
    const float* order = (const float*)d_in[1];
    float* out = (float*)d_out;
    char*  ws  = (char*)d_ws;
    const int write_complex = (out_size >= 2 * ROWS * NN) ? 1 : 0;

    hipLaunchKernelGGL(build_tables_k, dim3(16), dim3(256), 0, stream, order, ws);
    hipLaunchKernelGGL(g_fft_k, dim3(2), dim3(512), 0, stream, ws);
    hipLaunchKernelGGL(row_k, dim3(ROWS), dim3(512), 0, stream, x, ws, out, write_complex);
}

// Round 6
// 131.286 us; speedup vs baseline: 8.6986x; 1.3086x over previous
//
#include <hip/hip_runtime.h>
#include <math.h>

#ifndef M_PI
#define M_PI 3.14159265358979323846
#endif

#define ROWS 128
#define NN   4096

// ws byte offsets
#define TW_OFF   0        // float2[8192]  tw[k] = exp(-2*pi*i*k/8192)
#define CA_OFF   65536    // float2[8192]  cA[m] = chirp[4096+m]
#define GEIN_OFF 131072   // float2[8192]  Ec_even (time domain, natural)
#define GOIN_OFF 196608   // float2[8192]  Ec_odd  (time domain, natural)
#define GE_OFF   262144   // float2[8192]  DIF8192(Ec_even)  (scrambled order)
#define GO_OFF   327680   // float2[8192]  DIF8192(Ec_odd)   (scrambled order)
#define SC_OFF   393216   // float2        Aphi/128

// LDS bank-conflict swizzle (bijective within [0,8192))
__device__ __forceinline__ int swz(int i) { return i ^ ((i >> 5) & 31); }

// base-4 digit reversal of a 12-bit value (6 digits)
__device__ __forceinline__ int drev6(int v) {
    unsigned r = __brev((unsigned)v) >> 20;               // 12-bit bit reversal
    return (int)(((r & 0x555u) << 1) | ((r & 0xAAAu) >> 1)); // swap bit pairs
}

// ---- radix-2 stage, span 8192 (DIF: first / DIT: last) ----
template<int INV>
__device__ __forceinline__ void r2_8192(float* re, float* im,
                                        const float2* __restrict__ tw, int tid) {
    __syncthreads();
#pragma unroll
    for (int it = 0; it < 4; ++it) {
        const int n = tid + it * 1024;
        const int i0 = swz(n), i1 = swz(n + 4096);
        const float ur = re[i0], ui = im[i0];
        const float vr = re[i1], vi = im[i1];
        const float2 w = tw[n];
        const float wi = INV ? -w.y : w.y;
        if (!INV) {
            const float dr = ur - vr, di = ui - vi;
            re[i0] = ur + vr;            im[i0] = ui + vi;
            re[i1] = dr * w.x - di * wi; im[i1] = dr * wi + di * w.x;
        } else {
            const float br = vr * w.x - vi * wi, bi = vr * wi + vi * w.x;
            re[i0] = ur + br; im[i0] = ui + bi;
            re[i1] = ur - br; im[i1] = ui - bi;
        }
    }
}

// ---- radix-4 stage, span S = 1<<LS ----
template<int INV, int LS>
__device__ __forceinline__ void r4_stage(float* re, float* im,
                                         const float2* __restrict__ tw, int tid) {
    __syncthreads();
    const int Q = 1 << (LS - 2);
    const int TS = 13 - LS;
#pragma unroll
    for (int it = 0; it < 2; ++it) {
        const int gi = tid + it * 1024;
        const int q  = gi & (Q - 1);
        const int base = ((gi >> (LS - 2)) << LS) | q;
        const int i0 = swz(base), i1 = swz(base + Q), i2 = swz(base + 2 * Q), i3 = swz(base + 3 * Q);
        float ar = re[i0], ai = im[i0];
        float br = re[i1], bi = im[i1];
        float cr = re[i2], ci = im[i2];
        float dr = re[i3], di = im[i3];
        const float2 w1 = tw[q << TS];
        const float2 w2 = tw[(2 * q) << TS];
        const float2 w3 = tw[(3 * q) << TS];
        const float w1i = INV ? -w1.y : w1.y;
        const float w2i = INV ? -w2.y : w2.y;
        const float w3i = INV ? -w3.y : w3.y;
        if (!INV) {
            const float t0r = ar + cr, t0i = ai + ci;
            const float t1r = ar - cr, t1i = ai - ci;
            const float t2r = br + dr, t2i = bi + di;
            const float t3r = br - dr, t3i = bi - di;
            re[i0] = t0r + t2r; im[i0] = t0i + t2i;
            const float y1r = t1r + t3i, y1i = t1i - t3r;   // (t1 - i*t3)
            re[i1] = y1r * w1.x - y1i * w1i; im[i1] = y1r * w1i + y1i * w1.x;
            const float y2r = t0r - t2r, y2i = t0i - t2i;
            re[i2] = y2r * w2.x - y2i * w2i; im[i2] = y2r * w2i + y2i * w2.x;
            const float y3r = t1r - t3i, y3i = t1i + t3r;   // (t1 + i*t3)
            re[i3] = y3r * w3.x - y3i * w3i; im[i3] = y3r * w3i + y3i * w3.x;
        } else {
            const float b1r = br * w1.x - bi * w1i, b1i = br * w1i + bi * w1.x;
            const float b2r = cr * w2.x - ci * w2i, b2i = cr * w2i + ci * w2.x;
            const float b3r = dr * w3.x - di * w3i, b3i = dr * w3i + di * w3.x;
            const float s0r = ar + b2r, s0i = ai + b2i;
            const float s1r = ar - b2r, s1i = ai - b2i;
            const float s2r = b1r + b3r, s2i = b1i + b3i;
            const float s3r = b1r - b3r, s3i = b1i - b3i;
            re[i0] = s0r + s2r; im[i0] = s0i + s2i;
            re[i1] = s1r - s3i; im[i1] = s1i + s3r;         // s1 + i*s3
            re[i2] = s0r - s2r; im[i2] = s0i - s2i;
            re[i3] = s1r + s3i; im[i3] = s1i - s3r;         // s1 - i*s3
        }
    }
}

__device__ __forceinline__ void dif8192(float* re, float* im,
                                        const float2* __restrict__ tw, int tid) {
    r2_8192<0>(re, im, tw, tid);
    r4_stage<0, 12>(re, im, tw, tid);
    r4_stage<0, 10>(re, im, tw, tid);
    r4_stage<0, 8>(re, im, tw, tid);
    r4_stage<0, 6>(re, im, tw, tid);
    r4_stage<0, 4>(re, im, tw, tid);
    r4_stage<0, 2>(re, im, tw, tid);
}

__device__ __forceinline__ void dit8192(float* re, float* im,
                                        const float2* __restrict__ tw, int tid) {
    r4_stage<1, 2>(re, im, tw, tid);
    r4_stage<1, 4>(re, im, tw, tid);
    r4_stage<1, 6>(re, im, tw, tid);
    r4_stage<1, 8>(re, im, tw, tid);
    r4_stage<1, 10>(re, im, tw, tid);
    r4_stage<1, 12>(re, im, tw, tid);
    r2_8192<1>(re, im, tw, tid);
}

__global__ __launch_bounds__(256) void build_tables_k(const float* __restrict__ order,
                                                      char* __restrict__ ws) {
    const int gid  = blockIdx.x * 256 + threadIdx.x;
    const int nthr = gridDim.x * 256;
    const double a    = (double)order[0];
    const double phi  = a * (M_PI * 0.5);
    const double sp   = sin(phi);
    const double alph = -M_PI * tan(phi * 0.5);
    const double beta = M_PI / sp;
    float2* tw   = (float2*)(ws + TW_OFF);
    float2* cA   = (float2*)(ws + CA_OFF);
    float2* gein = (float2*)(ws + GEIN_OFF);
    float2* goin = (float2*)(ws + GOIN_OFF);
    float2* sc   = (float2*)(ws + SC_OFF);
    for (int k = gid; k < 8192; k += nthr) {
        double th = -2.0 * M_PI * (double)k / 8192.0;
        tw[k] = make_float2((float)cos(th), (float)sin(th));
    }
    for (int m = gid; m < 8192; m += nthr) {
        double xg = (double)(m - 4096) * (1.0 / 128.0);
        double th = alph * xg * xg;
        cA[m] = make_float2((float)cos(th), (float)sin(th));
    }
    for (int q = gid; q < 8192; q += nthr) {
        double de = (q < 4096) ? (double)(2 * q) : (double)(2 * q - 16384);
        double u  = de * (1.0 / 128.0);
        double te = beta * u * u;
        gein[q] = make_float2((float)cos(te), (float)sin(te));
        double dl = (q < 4096) ? (double)(2 * q - 1) : (double)(2 * q - 16385);
        double v  = dl * (1.0 / 128.0);
        double to = beta * v * v;
        goin[q] = make_float2((float)cos(to), (float)sin(to));
    }
    if (gid == 0) {
        double sgn = (sp >= 0.0) ? 1.0 : -1.0;
        double ang = -(M_PI * sgn * 0.25 - phi * 0.5);
        double amp = 1.0 / sqrt(fabs(sp));
        sc[0] = make_float2((float)(cos(ang) * amp / 128.0),
                            (float)(sin(ang) * amp / 128.0));
    }
}

// FFT the two conv kernels once (scrambled DIF order): block0 -> GE, block1 -> GO
__global__ __launch_bounds__(1024) void g_fft_k(char* __restrict__ ws) {
    __shared__ float re[8192];
    __shared__ float im[8192];
    const float2* tw  = (const float2*)(ws + TW_OFF);
    const float2* src = (const float2*)(ws + (blockIdx.x == 0 ? GEIN_OFF : GOIN_OFF));
    float2*       dst = (float2*)      (ws + (blockIdx.x == 0 ? GE_OFF   : GO_OFF));
    const int t = threadIdx.x;
#pragma unroll
    for (int j = 0; j < 8; ++j) {
        const int i = t + 1024 * j;
        const float2 v = src[i];
        re[swz(i)] = v.x; im[swz(i)] = v.y;
    }
    dif8192(re, im, tw, t);
    __syncthreads();
#pragma unroll
    for (int j = 0; j < 8; ++j) {
        const int i = t + 1024 * j;
        dst[i] = make_float2(re[swz(i)], im[swz(i)]);
    }
}

__global__ __launch_bounds__(1024) void row_k(const float* __restrict__ x,
                                              const char* __restrict__ ws,
                                              float* __restrict__ out,
                                              int write_complex) {
    __shared__ float re[8192];
    __shared__ float im[8192];
    const float2* tw = (const float2*)(ws + TW_OFF);
    const float2* cA = (const float2*)(ws + CA_OFF);
    const float2* GE = (const float2*)(ws + GE_OFF);
    const float2* GO = (const float2*)(ws + GO_OFF);
    const float2  sc = *(const float2*)(ws + SC_OFF);
    const int row = blockIdx.x;
    const int t   = threadIdx.x;

    // (1) load zero-interleaved u: u[2i]=x[i], u[2i+1]=0
#pragma unroll
    for (int j = 0; j < 4; ++j) {
        const int i = t + 1024 * j;
        const float v = x[row * NN + i];
        re[swz(2 * i)] = v;      im[swz(2 * i)] = 0.f;
        re[swz(2 * i + 1)] = 0.f; im[swz(2 * i + 1)] = 0.f;
    }

    // (2) forward FFT (scrambled output)
    dif8192(re, im, tw, t);

    // (3) spectral mask in scrambled order (+ fold 2/8192 scale)
    __syncthreads();
    const float s2 = 2.0f / 8192.0f;
#pragma unroll
    for (int j = 0; j < 8; ++j) {
        const int p = t + 1024 * j;
        const int d = drev6(p & 4095);
        const float f = (d < 1024 || d >= 3072) ? s2 : 0.f;
        const int idx = swz(p);
        re[idx] *= f; im[idx] *= f;
    }

    // (4) inverse FFT -> biz (natural order, real part in re)
    dit8192(re, im, tw, t);

    // (5) w build: gather biz, form w_even (to LDS) and stash w_odd (regs)
    __syncthreads();
    float wer[4], wei[4], wor[4], woi[4];
#pragma unroll
    for (int j = 0; j < 4; ++j) {
        const int q = t + 1024 * j;
        const float be = re[swz(2 * q)];
        const float bo = re[swz(2 * q + 1)];
        const float2 ce = cA[2 * q];
        const float2 co = cA[2 * q + 1];
        wer[j] = be * ce.x; wei[j] = be * ce.y;
        wor[j] = bo * co.x; woi[j] = bo * co.y;
    }
    __syncthreads();
#pragma unroll
    for (int j = 0; j < 4; ++j) {
        const int q = t + 1024 * j;
        re[swz(q)] = wer[j];          im[swz(q)] = wei[j];
        re[swz(q + 4096)] = 0.f;      im[swz(q + 4096)] = 0.f;
    }

    // (6) FFT w_even
    dif8192(re, im, tw, t);

    // (7) stash ye = What_e * GE (own slots)
    __syncthreads();
    float yer[8], yei[8];
#pragma unroll
    for (int j = 0; j < 8; ++j) {
        const int p = t + 1024 * j;
        const int idx = swz(p);
        const float2 g = GE[p];
        const float wr = re[idx], wi_ = im[idx];
        yer[j] = wr * g.x - wi_ * g.y;
        yei[j] = wr * g.y + wi_ * g.x;
    }

    // (8) write w_odd
    __syncthreads();
#pragma unroll
    for (int j = 0; j < 4; ++j) {
        const int q = t + 1024 * j;
        re[swz(q)] = wor[j];          im[swz(q)] = woi[j];
        re[swz(q + 4096)] = 0.f;      im[swz(q + 4096)] = 0.f;
    }

    // (9) FFT w_odd
    dif8192(re, im, tw, t);

    // (10) Y = ye + What_o * GO
    __syncthreads();
#pragma unroll
    for (int j = 0; j < 8; ++j) {
        const int p = t + 1024 * j;
        const int idx = swz(p);
        const float2 g = GO[p];
        const float wr = re[idx], wi_ = im[idx];
        re[idx] = yer[j] + wr * g.x - wi_ * g.y;
        im[idx] = yei[j] + wr * g.y + wi_ * g.x;
    }

    // (11) inverse FFT -> y (natural, x8192)
    dit8192(re, im, tw, t);

    // (12) output
    __syncthreads();
    const float is = 1.0f / 8192.0f;
#pragma unroll
    for (int j = 0; j < 4; ++j) {
        const int o = t + 1024 * j;
        const int idx = swz(o);
        const float vr = re[idx] * is, vi = im[idx] * is;
        const float2 c = cA[2 * o];
        const float tr = vr * c.x - vi * c.y;
        const float ti = vr * c.y + vi * c.x;
        float rr = tr * sc.x - ti * sc.y;
        float ri = tr * sc.y + ti * sc.x;
        if (o == 0) { rr *= 2.f; ri *= 2.f; }
        const int gi = row * NN + o;
        if (write_complex) { out[2 * gi] = rr; out[2 * gi + 1] = ri; }
        else               { out[gi] = rr; }
    }
}

extern "C" void kernel_launch(void* const* d_in, const int* in_sizes, int n_in,
                              void* d_out, int out_size, void* d_ws, size_t ws_size,
                              hipStream_t stream) {
    const float* x     = (const float*)d_in[0];
    const float* order = (const float*)d_in[1];
    float* out = (float*)d_out;
    char*  ws  = (char*)d_ws;
    const int write_complex = (out_size >= 2 * ROWS * NN) ? 1 : 0;

    hipLaunchKernelGGL(build_tables_k, dim3(64), dim3(256), 0, stream, order, ws);
    hipLaunchKernelGGL(g_fft_k, dim3(2), dim3(1024), 0, stream, ws);
    hipLaunchKernelGGL(row_k, dim3(ROWS), dim3(1024), 0, stream, x, ws, out, write_complex);
}